// Round 11
// baseline (58.265 us; speedup 1.0000x reference)
//
#include <hip/hip_runtime.h>

typedef _Float16 half_t;
typedef _Float16 half8 __attribute__((ext_vector_type(8)));
typedef float    f32x4 __attribute__((ext_vector_type(4)));

#define NLEN   8388608
#define KTAPS  257
#define MPAD   256
#define OUTLEN (NLEN + MPAD)        /* 8388864 */
#define NT     32769                /* 16x16 output tiles (256 outputs each) */
#define NCH    9                    /* GEMM-K = 288 */
#define AFSLOT (2 * NCH * 64)       /* 1152 half8 = 18432 B */
#define PLEN   (OUTLEN + 576)       /* padded fp16 plane elems (mult of 8) */
#define PSLOT  (PLEN / 8)
#define PLBYTES ((size_t)PLEN * 2)
#define AFOFF  (2 * PLBYTES)
#define WSNEED (AFOFF + (size_t)AFSLOT * 16)

#define MFMA __builtin_amdgcn_mfma_f32_16x16x32_f16

/* ---------- build weight-fragment table in ws ---------- */
__global__ __launch_bounds__(256) void build_af(
    const float* __restrict__ wr, const float* __restrict__ wi,
    half8* __restrict__ af)
{
    for (int i = threadIdx.x; i < AFSLOT; i += 256) {
        const int comp = i / (NCH * 64);
        const int rem  = i % (NCH * 64);
        const int c    = rem >> 6;
        const int l    = rem & 63;
        const int row  = l & 15;
        const int jb   = 32 * c + 8 * (l >> 4);
        const float* wp = comp ? wi : wr;
        half8 v;
        #pragma unroll
        for (int e = 0; e < 8; ++e) {
            const int k = jb + e - row;
            const float f = (k >= 0 && k < KTAPS) ? wp[k] : 0.0f;
            v[e] = (_Float16)f;
        }
        af[i] = v;
    }
}

/* ---------- pass 1: fp32 -> zero-padded fp16 planes in ws ---------- */
__global__ __launch_bounds__(256) void cvt_planes(
    const float* __restrict__ xr, const float* __restrict__ xi,
    half_t* __restrict__ pr, half_t* __restrict__ pi)
{
    const int idx = blockIdx.x * 256 + threadIdx.x;
    if (idx >= PSLOT) return;
    const int g = idx * 8 - MPAD;       /* signal index of first elem */
    half8 vr, vi;
    if (g >= 0 && g + 8 <= NLEN) {
        const f32x4 a0 = *(const f32x4*)(xr + g);
        const f32x4 a1 = *(const f32x4*)(xr + g + 4);
        const f32x4 b0 = *(const f32x4*)(xi + g);
        const f32x4 b1 = *(const f32x4*)(xi + g + 4);
        #pragma unroll
        for (int e = 0; e < 4; ++e) {
            vr[e]     = (_Float16)a0[e];
            vr[e + 4] = (_Float16)a1[e];
            vi[e]     = (_Float16)b0[e];
            vi[e + 4] = (_Float16)b1[e];
        }
    } else {
        #pragma unroll
        for (int e = 0; e < 8; ++e) {
            const int ge = g + e;
            const bool ok = (ge >= 0) && (ge < NLEN);
            vr[e] = (_Float16)(ok ? xr[ge] : 0.0f);
            vi[e] = (_Float16)(ok ? xi[ge] : 0.0f);
        }
    }
    *(half8*)(pr + idx * 8) = vr;
    *(half8*)(pi + idx * 8) = vi;
}

/* ---------- pass 2: barrier-free MFMA, B-frags direct from global fp16 ----------
   Wave owns 2 consecutive 16x16 tiles; weights from block-shared LDS (one
   barrier at start only). 4 accumulators per tile -> zero in-loop negation:
   y_r = P - Q, y_i = R + S. Loads for out-of-range tail tiles stay inside the
   ws allocation (pad + following regions); their results are store-guarded. */
__global__ __launch_bounds__(256, 4) void cconv_p2(
    const half_t* __restrict__ pr, const half_t* __restrict__ pi,
    const half8* __restrict__ af, float* __restrict__ out)
{
    __shared__ half8 afl[AFSLOT];

    const int tid  = threadIdx.x;
    const int wv   = tid >> 6;
    const int lane = tid & 63;
    const int n15  = lane & 15;
    const int lg   = lane >> 4;

    for (int i = tid; i < AFSLOT; i += 256) afl[i] = af[i];
    __syncthreads();                       /* the only barrier */

    const int tt0 = blockIdx.x * 8 + wv * 2;     /* this wave's first tile */
    const int lane_off = 16 * n15 + 8 * lg;
    const half_t* prA = pr + (size_t)tt0 * 256 + lane_off;
    const half_t* piA = pi + (size_t)tt0 * 256 + lane_off;

    f32x4 P0 = (f32x4)0.0f, Q0 = (f32x4)0.0f, R0 = (f32x4)0.0f, S0 = (f32x4)0.0f;
    f32x4 P1 = (f32x4)0.0f, Q1 = (f32x4)0.0f, R1 = (f32x4)0.0f, S1 = (f32x4)0.0f;

    #pragma unroll
    for (int c = 0; c < NCH; ++c) {
        const half8 awr = afl[c * 64 + lane];
        const half8 awi = afl[NCH * 64 + c * 64 + lane];
        const half8 br0 = *(const half8*)(prA + 32 * c);
        const half8 bi0 = *(const half8*)(piA + 32 * c);
        const half8 br1 = *(const half8*)(prA + 32 * c + 256);
        const half8 bi1 = *(const half8*)(piA + 32 * c + 256);
        P0 = MFMA(awr, br0, P0, 0, 0, 0);
        S0 = MFMA(awi, br0, S0, 0, 0, 0);
        R0 = MFMA(awr, bi0, R0, 0, 0, 0);
        Q0 = MFMA(awi, bi0, Q0, 0, 0, 0);
        P1 = MFMA(awr, br1, P1, 0, 0, 0);
        S1 = MFMA(awi, br1, S1, 0, 0, 0);
        R1 = MFMA(awr, bi1, R1, 0, 0, 0);
        Q1 = MFMA(awi, bi1, Q1, 0, 0, 0);
    }

    const int pos0 = tt0 * 256 + 16 * n15 + 4 * lg;
    if (tt0 < NT) {
        *(f32x4*)(out + pos0)          = P0 - Q0;
        *(f32x4*)(out + OUTLEN + pos0) = R0 + S0;
    }
    if (tt0 + 1 < NT) {
        *(f32x4*)(out + pos0 + 256)          = P1 - Q1;
        *(f32x4*)(out + OUTLEN + pos0 + 256) = R1 + S1;
    }
}

/* ---------- fallback (no/small ws): R3-shape single-stage, af in LDS ---------- */
#define FTPB   256
#define FBT    4096
#define FNBLK  ((OUTLEN + FBT - 1) / FBT)
#define FXSLOT ((FBT + 288) / 8)
#define FXPAD  556

__device__ __forceinline__ int fswz(int t) { return t ^ ((t >> 3) & 7); }

__global__ __launch_bounds__(FTPB, 4) void cconv_local(
    const float* __restrict__ xr, const float* __restrict__ xi,
    const float* __restrict__ wr, const float* __restrict__ wi,
    float* __restrict__ out)
{
    __shared__ half8 lx[2][FXPAD];
    __shared__ half8 afl[2][NCH][64];

    const int tid   = threadIdx.x;
    const int wv    = tid >> 6;
    const int lane  = tid & 63;
    const int n15   = lane & 15;
    const int lg    = lane >> 4;
    const int t0    = blockIdx.x * FBT;
    const int xbase = t0 - MPAD;

    for (int i = tid; i < AFSLOT; i += FTPB) {
        const int comp = i / (NCH * 64);
        const int rem  = i % (NCH * 64);
        const int c    = rem >> 6;
        const int l    = rem & 63;
        const int row  = l & 15;
        const int jb   = 32 * c + 8 * (l >> 4);
        const float* wp = comp ? wi : wr;
        half8 v;
        #pragma unroll
        for (int e = 0; e < 8; ++e) {
            const int k = jb + e - row;
            const float f = (k >= 0 && k < KTAPS) ? wp[k] : 0.0f;
            v[e] = (_Float16)f;
        }
        afl[comp][c][l] = v;
    }
    for (int T = tid; T < FXSLOT; T += FTPB) {
        const int g = xbase + 8 * T;
        half8 vr, vi;
        if (g >= 0 && g + 8 <= NLEN) {
            const f32x4 a0 = *(const f32x4*)(xr + g);
            const f32x4 a1 = *(const f32x4*)(xr + g + 4);
            const f32x4 b0 = *(const f32x4*)(xi + g);
            const f32x4 b1 = *(const f32x4*)(xi + g + 4);
            #pragma unroll
            for (int e = 0; e < 4; ++e) {
                vr[e]     = (_Float16)a0[e];
                vr[e + 4] = (_Float16)a1[e];
                vi[e]     = (_Float16)b0[e];
                vi[e + 4] = (_Float16)b1[e];
            }
        } else {
            #pragma unroll
            for (int e = 0; e < 8; ++e) {
                const int ge = g + e;
                const bool ok = (ge >= 0) && (ge < NLEN);
                vr[e] = (_Float16)(ok ? xr[ge] : 0.0f);
                vi[e] = (_Float16)(ok ? xi[ge] : 0.0f);
            }
        }
        const int Ts = fswz(T);
        lx[0][Ts] = vr;
        lx[1][Ts] = vi;
    }
    __syncthreads();

    f32x4 accr[4], acci[4];
    #pragma unroll
    for (int t = 0; t < 4; ++t) { accr[t] = (f32x4)0.0f; acci[t] = (f32x4)0.0f; }

    const int sT0 = 128 * wv + 2 * n15 + lg;

    #pragma unroll
    for (int c = 0; c < NCH; ++c) {
        const half8 awr  = afl[0][c][lane];
        const half8 awi  = afl[1][c][lane];
        const half8 awin = -awi;
        #pragma unroll
        for (int t = 0; t < 4; ++t) {
            const int Ts = fswz(sT0 + 32 * t + 4 * c);
            const half8 br = lx[0][Ts];
            const half8 bi = lx[1][Ts];
            accr[t] = MFMA(awr,  br, accr[t], 0, 0, 0);
            accr[t] = MFMA(awin, bi, accr[t], 0, 0, 0);
            acci[t] = MFMA(awr,  bi, acci[t], 0, 0, 0);
            acci[t] = MFMA(awi,  br, acci[t], 0, 0, 0);
        }
    }

    const int obase = t0 + 1024 * wv + 16 * n15 + 4 * lg;
    #pragma unroll
    for (int t = 0; t < 4; ++t) {
        const int tbase = t0 + 1024 * wv + 256 * t;
        if (tbase < OUTLEN) {
            const int pos = obase + 256 * t;
            *(f32x4*)(out + pos)          = accr[t];
            *(f32x4*)(out + OUTLEN + pos) = acci[t];
        }
    }
}

extern "C" void kernel_launch(void* const* d_in, const int* in_sizes, int n_in,
                              void* d_out, int out_size, void* d_ws, size_t ws_size,
                              hipStream_t stream) {
    const float* xr = (const float*)d_in[0];
    const float* xi = (const float*)d_in[1];
    const float* wr = (const float*)d_in[2];
    const float* wi = (const float*)d_in[3];
    float* o = (float*)d_out;
    if (ws_size >= WSNEED) {
        half_t* pr = (half_t*)d_ws;
        half_t* pi = (half_t*)((char*)d_ws + PLBYTES);
        half8*  af = (half8*)((char*)d_ws + AFOFF);
        build_af<<<1, 256, 0, stream>>>(wr, wi, af);
        cvt_planes<<<(PSLOT + 255) / 256, 256, 0, stream>>>(xr, xi, pr, pi);
        cconv_p2<<<(NT + 7) / 8, 256, 0, stream>>>(pr, pi, af, o);
    } else {
        cconv_local<<<FNBLK, FTPB, 0, stream>>>(xr, xi, wr, wi, o);
    }
}